// Round 11
// baseline (276.078 us; speedup 1.0000x reference)
//
#include <hip/hip_runtime.h>

#define BB 2
#define SS 2048
#define DD 1024
#define HH 16
#define DKK 64
#define MROWS (BB*SS)
#define NEG_BIG (-30000.0f)

typedef unsigned short u16;
typedef unsigned int u32;
typedef __bf16 bf16x8 __attribute__((ext_vector_type(8)));
typedef float f32x4 __attribute__((ext_vector_type(4)));

__device__ __forceinline__ u16 f2bf(float f) {
    union { float f; u32 i; } w; w.f = f;
    u32 u = w.i;
    return (u16)((u + 0x7fffu + ((u >> 16) & 1u)) >> 16);
}
__device__ __forceinline__ float bf2f(u16 u) {
    union { u32 i; float f; } w; w.i = ((u32)u) << 16; return w.f;
}
__device__ __forceinline__ u32 pack2(float lo, float hi) {
    union { float f; u32 i; } a, b; a.f = lo; b.f = hi;
    return (a.i >> 16) | (b.i & 0xffff0000u);
}
__device__ __forceinline__ void gl2lds16(const u16* g, u16* l) {
    __builtin_amdgcn_global_load_lds(
        (const __attribute__((address_space(1))) void*)g,
        (__attribute__((address_space(3))) void*)l, 16, 0, 0);
}

// ---------------------------------------------------------------------------
// f32 -> bf16 converters.
// ---------------------------------------------------------------------------
__global__ __launch_bounds__(256)
void cvt_w(const float* __restrict__ w0, const float* __restrict__ w1,
           const float* __restrict__ w2, const float* __restrict__ w3,
           u16* __restrict__ dst)
{
    const float* srcs[4] = {w0, w1, w2, w3};
    const float* s = srcs[blockIdx.y];
    int i = (blockIdx.x * 256 + threadIdx.x) * 8;
    float4 a = *(const float4*)(s + i);
    float4 b = *(const float4*)(s + i + 4);
    uint4 o;
    o.x = pack2(a.x, a.y); o.y = pack2(a.z, a.w);
    o.z = pack2(b.x, b.y); o.w = pack2(b.z, b.w);
    *(uint4*)(dst + (size_t)blockIdx.y * DD * DD + i) = o;
}

__global__ __launch_bounds__(256)
void cvt_x(const float* __restrict__ s, u16* __restrict__ dst)
{
    int i = (blockIdx.x * 256 + threadIdx.x) * 8;
    float4 a = *(const float4*)(s + i);
    float4 b = *(const float4*)(s + i + 4);
    uint4 o;
    o.x = pack2(a.x, a.y); o.y = pack2(a.z, a.w);
    o.z = pack2(b.x, b.y); o.w = pack2(b.z, b.w);
    *(uint4*)(dst + i) = o;
}

// ---------------------------------------------------------------------------
// Fused QKV GEMM: grid (256, 3). y selects {Q,K,V}. A read as f32 and packed
// to bf16 during staging. W via global_load_lds. XOR-swizzled LDS.
// XCD-locality: bm = (blk&7)*4 + ((blk>>3)&3), bn = blk>>5 -> all 8 bn-tiles
// of one bm share an XCD's L2 (A-tile fetched once per XCD, not 8x).
// ---------------------------------------------------------------------------
__global__ __launch_bounds__(256, 3)
void qkv_gemm(const float* __restrict__ qf, const float* __restrict__ kf,
              const float* __restrict__ vf, const u16* __restrict__ wbf,
              const float* __restrict__ bq, const float* __restrict__ bk,
              const float* __restrict__ bv,
              u16* __restrict__ qh, u16* __restrict__ kh, u16* __restrict__ vt)
{
    __shared__ __align__(16) u16 smem[16384];
    u16* As = smem;
    u16* Bs = smem + 8192;
    const int K = 1024;
    int y = blockIdx.y;
    const float* A = (y == 0) ? qf : (y == 1) ? kf : vf;
    const u16* Wb = wbf + (size_t)y * DD * DD;
    const float* bias = (y == 0) ? bq : (y == 1) ? bk : bv;
    u16* out = (y == 0) ? qh : (y == 1) ? kh : vt;

    int tid  = threadIdx.x;
    int wave = tid >> 6, lane = tid & 63;
    int quad = lane >> 4, l16 = lane & 15;
    int blk = blockIdx.x;
    int bm = (blk & 7) * 4 + ((blk >> 3) & 3);   // XCD-pinned A-tile group
    int bn = blk >> 5;
    int row0 = bm * 128, col0 = bn * 128;
    int wm = (wave >> 1) * 64, wn = (wave & 1) * 64;

    int srow = tid >> 3;
    int scol = (tid & 7) * 8;
    int swz  = ((tid & 7) ^ ((tid >> 3) & 7)) * 8;
    int bswz = ((lane & 7) ^ ((lane >> 3) & 7)) * 8;

    f32x4 acc[4][4] = {};

    for (int k0 = 0; k0 < K; k0 += 64) {
        uint4 av[4];
        #pragma unroll
        for (int c = 0; c < 4; ++c) {
            const float* ap = A + (size_t)(row0 + srow + c * 32) * K + k0 + scol;
            float4 lo = *(const float4*)ap;
            float4 hi = *(const float4*)(ap + 4);
            av[c].x = pack2(lo.x, lo.y); av[c].y = pack2(lo.z, lo.w);
            av[c].z = pack2(hi.x, hi.y); av[c].w = pack2(hi.z, hi.w);
        }
        __syncthreads();
        #pragma unroll
        for (int c = 0; c < 4; ++c)
            *(uint4*)&As[(srow + c * 32) * 64 + swz] = av[c];
        #pragma unroll
        for (int c = 0; c < 4; ++c) {
            int r0 = (c * 4 + wave) * 8;
            gl2lds16(Wb + (size_t)(col0 + r0 + (lane >> 3)) * K + k0 + bswz,
                     Bs + r0 * 64);
        }
        __syncthreads();
        #pragma unroll
        for (int kk = 0; kk < 2; ++kk) {
            bf16x8 af[4], bfv[4];
            #pragma unroll
            for (int i = 0; i < 4; ++i)
                af[i] = *(const bf16x8*)&As[(wm + i * 16 + l16) * 64 +
                                            (((kk * 4 + quad) ^ (l16 & 7)) * 8)];
            #pragma unroll
            for (int j = 0; j < 4; ++j)
                bfv[j] = *(const bf16x8*)&Bs[(wn + j * 16 + l16) * 64 +
                                             (((kk * 4 + quad) ^ (l16 & 7)) * 8)];
            #pragma unroll
            for (int i = 0; i < 4; ++i)
                #pragma unroll
                for (int j = 0; j < 4; ++j)
                    acc[i][j] = __builtin_amdgcn_mfma_f32_16x16x32_bf16(af[i], bfv[j], acc[i][j], 0, 0, 0);
        }
    }

    if (y == 2) {
        u16* Ct = smem;   // [dk 64][s 128] stride 136
        int b = row0 >> 11;
        int s0 = row0 & (SS - 1);
        #pragma unroll
        for (int p = 0; p < 2; ++p) {
            __syncthreads();
            if ((wave & 1) == p) {
                #pragma unroll
                for (int j = 0; j < 4; ++j) {
                    int dkl = j * 16 + l16;
                    float bvv = bias[col0 + p * 64 + dkl];
                    #pragma unroll
                    for (int i = 0; i < 4; ++i) {
                        uint2 pw;
                        pw.x = pack2(acc[i][j][0] + bvv, acc[i][j][1] + bvv);
                        pw.y = pack2(acc[i][j][2] + bvv, acc[i][j][3] + bvv);
                        *(uint2*)&Ct[dkl * 136 + wm + i * 16 + quad * 4] = pw;
                    }
                }
            }
            __syncthreads();
            int dkl = tid >> 2, seg = (tid & 3) * 32;
            int n = col0 + p * 64 + dkl;
            int h = n >> 6, dk = n & 63;
            u16* dst = out + (((size_t)(b * HH + h)) * DKK + dk) * SS + s0 + seg;
            #pragma unroll
            for (int u = 0; u < 4; ++u)
                *(uint4*)(dst + u * 8) = *(const uint4*)&Ct[dkl * 136 + seg + u * 8];
        }
        return;
    }

    #pragma unroll
    for (int j = 0; j < 4; ++j) {
        int n = col0 + wn + j * 16 + l16;
        float bvv = bias[n];
        #pragma unroll
        for (int i = 0; i < 4; ++i) {
            int rbase = row0 + wm + i * 16 + quad * 4;
            #pragma unroll
            for (int r = 0; r < 4; ++r) {
                int m = rbase + r;
                int b = m >> 11, s = m & (SS - 1);
                int h = n >> 6, dk = n & 63;
                out[(((size_t)(b * HH + h)) * SS + s) * DKK + dk] = f2bf(acc[i][j][r] + bvv);
            }
        }
    }
}

// ---------------------------------------------------------------------------
// Split-K O-proj: grid (256, 2); y = K-half. f32 partials. Swizzled LDS +
// XCD-locality block mapping.
// ---------------------------------------------------------------------------
__global__ __launch_bounds__(256, 3)
void gemm_osk(const u16* __restrict__ A, const u16* __restrict__ Wb,
              const float* __restrict__ bias, float* __restrict__ P)
{
    __shared__ __align__(16) u16 smem[16384];
    u16* As = smem;
    u16* Bs = smem + 8192;
    const int K = 1024;
    int khalf = blockIdx.y;
    int tid  = threadIdx.x;
    int wave = tid >> 6, lane = tid & 63;
    int quad = lane >> 4, l16 = lane & 15;
    int blk = blockIdx.x;
    int bm = (blk & 7) * 4 + ((blk >> 3) & 3);
    int bn = blk >> 5;
    int row0 = bm * 128, col0 = bn * 128;
    int wm = (wave >> 1) * 64, wn = (wave & 1) * 64;
    int bswz = ((lane & 7) ^ ((lane >> 3) & 7)) * 8;

    f32x4 acc[4][4] = {};

    for (int k0 = khalf * 512; k0 < khalf * 512 + 512; k0 += 64) {
        __syncthreads();
        #pragma unroll
        for (int c = 0; c < 4; ++c) {
            int r0 = (c * 4 + wave) * 8;
            gl2lds16(A  + (size_t)(row0 + r0 + (lane >> 3)) * K + k0 + bswz,
                     As + r0 * 64);
            gl2lds16(Wb + (size_t)(col0 + r0 + (lane >> 3)) * K + k0 + bswz,
                     Bs + r0 * 64);
        }
        __syncthreads();
        #pragma unroll
        for (int kk = 0; kk < 2; ++kk) {
            bf16x8 af[4], bfv[4];
            #pragma unroll
            for (int i = 0; i < 4; ++i)
                af[i] = *(const bf16x8*)&As[(wm + i * 16 + l16) * 64 +
                                            (((kk * 4 + quad) ^ (l16 & 7)) * 8)];
            #pragma unroll
            for (int j = 0; j < 4; ++j)
                bfv[j] = *(const bf16x8*)&Bs[(wn + j * 16 + l16) * 64 +
                                             (((kk * 4 + quad) ^ (l16 & 7)) * 8)];
            #pragma unroll
            for (int i = 0; i < 4; ++i)
                #pragma unroll
                for (int j = 0; j < 4; ++j)
                    acc[i][j] = __builtin_amdgcn_mfma_f32_16x16x32_bf16(af[i], bfv[j], acc[i][j], 0, 0, 0);
        }
    }

    float* Pd = P + (size_t)khalf * MROWS * DD;
    #pragma unroll
    for (int j = 0; j < 4; ++j) {
        int n = col0 + wn + j * 16 + l16;
        float bvv = (khalf == 0) ? bias[n] : 0.f;
        #pragma unroll
        for (int i = 0; i < 4; ++i) {
            int rbase = row0 + wm + i * 16 + quad * 4;
            #pragma unroll
            for (int r = 0; r < 4; ++r)
                Pd[(size_t)(rbase + r) * DD + n] = acc[i][j][r] + bvv;
        }
    }
}

// ---------------------------------------------------------------------------
// Layout-B GEMM (sequential fallback path; unswizzled, proven).
// ---------------------------------------------------------------------------
template<int MODE>
__global__ __launch_bounds__(256, 2)
void gemm_nt(const u16* __restrict__ A, const u16* __restrict__ Wb,
             const float* __restrict__ bias, u16* __restrict__ out)
{
    __shared__ __align__(16) u16 smem[16384];
    u16* As = smem;
    u16* Bs = smem + 8192;
    const int K = 1024;
    int tid  = threadIdx.x;
    int wave = tid >> 6, lane = tid & 63;
    int quad = lane >> 4, l16 = lane & 15;
    int bm = blockIdx.x >> 3;
    int bn = blockIdx.x & 7;
    int row0 = bm * 128, col0 = bn * 128;
    int wm = (wave >> 1) * 64, wn = (wave & 1) * 64;

    f32x4 acc[4][4] = {};

    for (int k0 = 0; k0 < K; k0 += 64) {
        __syncthreads();
        #pragma unroll
        for (int c = 0; c < 4; ++c) {
            int r0 = (c * 4 + wave) * 8;
            gl2lds16(A  + (size_t)(row0 + r0 + (lane >> 3)) * K + k0 + (lane & 7) * 8,
                     As + r0 * 64);
            gl2lds16(Wb + (size_t)(col0 + r0 + (lane >> 3)) * K + k0 + (lane & 7) * 8,
                     Bs + r0 * 64);
        }
        __syncthreads();
        #pragma unroll
        for (int kk = 0; kk < 2; ++kk) {
            bf16x8 af[4], bfv[4];
            #pragma unroll
            for (int i = 0; i < 4; ++i)
                af[i] = *(const bf16x8*)&As[(wm + i * 16 + l16) * 64 + kk * 32 + quad * 8];
            #pragma unroll
            for (int j = 0; j < 4; ++j)
                bfv[j] = *(const bf16x8*)&Bs[(wn + j * 16 + l16) * 64 + kk * 32 + quad * 8];
            #pragma unroll
            for (int i = 0; i < 4; ++i)
                #pragma unroll
                for (int j = 0; j < 4; ++j)
                    acc[i][j] = __builtin_amdgcn_mfma_f32_16x16x32_bf16(af[i], bfv[j], acc[i][j], 0, 0, 0);
        }
    }

    if (MODE == 2) {
        u16* Ct = smem;
        int b = row0 >> 11;
        int s0 = row0 & (SS - 1);
        #pragma unroll
        for (int p = 0; p < 2; ++p) {
            __syncthreads();
            if ((wave & 1) == p) {
                #pragma unroll
                for (int j = 0; j < 4; ++j) {
                    int dkl = j * 16 + l16;
                    float bvv = bias[col0 + p * 64 + dkl];
                    #pragma unroll
                    for (int i = 0; i < 4; ++i) {
                        uint2 pw;
                        pw.x = pack2(acc[i][j][0] + bvv, acc[i][j][1] + bvv);
                        pw.y = pack2(acc[i][j][2] + bvv, acc[i][j][3] + bvv);
                        *(uint2*)&Ct[dkl * 136 + wm + i * 16 + quad * 4] = pw;
                    }
                }
            }
            __syncthreads();
            int dkl = tid >> 2, seg = (tid & 3) * 32;
            int n = col0 + p * 64 + dkl;
            int h = n >> 6, dk = n & 63;
            u16* dst = out + (((size_t)(b * HH + h)) * DKK + dk) * SS + s0 + seg;
            #pragma unroll
            for (int u = 0; u < 4; ++u)
                *(uint4*)(dst + u * 8) = *(const uint4*)&Ct[dkl * 136 + seg + u * 8];
        }
        return;
    }

    #pragma unroll
    for (int j = 0; j < 4; ++j) {
        int n = col0 + wn + j * 16 + l16;
        float bvv = bias[n];
        #pragma unroll
        for (int i = 0; i < 4; ++i) {
            int rbase = row0 + wm + i * 16 + quad * 4;
            #pragma unroll
            for (int r = 0; r < 4; ++r) {
                int m = rbase + r;
                float v = acc[i][j][r] + bvv;
                if (MODE == 0) {
                    int b = m >> 11, s = m & (SS - 1);
                    int h = n >> 6, dk = n & 63;
                    out[(((size_t)(b * HH + h)) * SS + s) * DKK + dk] = f2bf(v);
                } else {
                    out[(size_t)m * DD + n] = f2bf(v);
                }
            }
        }
    }
}

// ---------------------------------------------------------------------------
// Flash attention v6 (round-10 proven): XOR-swizzled K/V LDS, block = 4 waves
// = 64 q-rows, K/V staged once per block, grid 1024 heavy-first.
// ---------------------------------------------------------------------------
__global__ __launch_bounds__(256, 3)
void attn6(const u16* __restrict__ Qh, const u16* __restrict__ Kh,
           const u16* __restrict__ Vt, const float* __restrict__ comp,
           const float* __restrict__ cpen_p, u16* __restrict__ ctx)
{
    __shared__ __align__(16) u16 Kl[64 * 64];
    __shared__ __align__(16) u16 Vtl[64 * 64];
    __shared__ __align__(16) u16 Pb[4][16 * 72];

    int tid  = threadIdx.x;
    int wave = tid >> 6, lane = tid & 63;
    int quad = lane >> 4, l16 = lane & 15;
    int blk = blockIdx.x;
    int bh  = blk & 31;
    int qt  = 31 - (blk >> 5);
    int q0  = qt * 64;
    int b = bh >> 4, h = bh & 15;
    float cpen = cpen_p[0];
    int lswz = ((lane & 7) ^ ((lane >> 3) & 7)) * 8;

    const u16* Qb = Qh + (size_t)bh * SS * DKK;
    const u16* Kb = Kh + (size_t)bh * SS * DKK;
    const u16* Vb = Vt + (size_t)bh * DKK * SS;

    int myq = q0 + wave * 16 + l16;
    bf16x8 qf0 = *(const bf16x8*)&Qb[(size_t)myq * DKK + quad * 8];
    bf16x8 qf1 = *(const bf16x8*)&Qb[(size_t)myq * DKK + 32 + quad * 8];

    f32x4 o[4] = {};
    float m_i = NEG_BIG, l_i = 0.f;

    for (int kt = 0; kt <= qt; ++kt) {
        __syncthreads();
        if (wave < 2) {
            #pragma unroll
            for (int c = 0; c < 4; ++c) {
                int idx = wave * 4 + c;
                gl2lds16(Kb + (size_t)kt * 4096 + idx * 512 + (lane >> 3) * 64 + lswz,
                         Kl + idx * 512);
            }
        } else {
            #pragma unroll
            for (int c = 0; c < 4; ++c) {
                int r0 = ((wave - 2) * 4 + c) * 8;
                gl2lds16(Vb + (size_t)(r0 + (lane >> 3)) * SS + kt * 64 + lswz,
                         Vtl + r0 * 64);
            }
        }
        __syncthreads();

        f32x4 sc[4] = {};
        #pragma unroll
        for (int jj = 0; jj < 4; ++jj) {
            bf16x8 kf0 = *(const bf16x8*)&Kl[(jj * 16 + l16) * 64 + ((quad ^ (l16 & 7)) * 8)];
            bf16x8 kf1 = *(const bf16x8*)&Kl[(jj * 16 + l16) * 64 + (((4 + quad) ^ (l16 & 7)) * 8)];
            sc[jj] = __builtin_amdgcn_mfma_f32_16x16x32_bf16(kf0, qf0, sc[jj], 0, 0, 0);
            sc[jj] = __builtin_amdgcn_mfma_f32_16x16x32_bf16(kf1, qf1, sc[jj], 0, 0, 0);
        }
        bool diag = (kt == qt);
        #pragma unroll
        for (int jj = 0; jj < 4; ++jj) {
            f32x4 c4 = *(const f32x4*)&comp[b * SS + kt * 64 + jj * 16 + quad * 4];
            int kb0 = kt * 64 + jj * 16 + quad * 4;
            #pragma unroll
            for (int r = 0; r < 4; ++r) {
                float sv = sc[jj][r] * 0.125f - cpen * c4[r];
                if (diag && (kb0 + r > myq)) sv = NEG_BIG;
                sc[jj][r] = sv;
            }
        }
        float mx = NEG_BIG;
        #pragma unroll
        for (int jj = 0; jj < 4; ++jj)
            #pragma unroll
            for (int r = 0; r < 4; ++r) mx = fmaxf(mx, sc[jj][r]);
        mx = fmaxf(mx, __shfl_xor(mx, 16, 64));
        mx = fmaxf(mx, __shfl_xor(mx, 32, 64));
        float mnew = fmaxf(m_i, mx);
        float alpha = __expf(m_i - mnew);
        m_i = mnew;
        float ls = 0.f;
        #pragma unroll
        for (int jj = 0; jj < 4; ++jj)
            #pragma unroll
            for (int r = 0; r < 4; ++r) {
                float p = __expf(sc[jj][r] - mnew);
                sc[jj][r] = p;
                ls += p;
            }
        ls += __shfl_xor(ls, 16, 64);
        ls += __shfl_xor(ls, 32, 64);
        l_i = l_i * alpha + ls;
        #pragma unroll
        for (int jj = 0; jj < 4; ++jj)
            #pragma unroll
            for (int r = 0; r < 4; ++r) o[jj][r] *= alpha;

        #pragma unroll
        for (int jj = 0; jj < 4; ++jj) {
            uint2 pw;
            pw.x = pack2(sc[jj][0], sc[jj][1]);
            pw.y = pack2(sc[jj][2], sc[jj][3]);
            *(uint2*)&Pb[wave][l16 * 72 + jj * 16 + quad * 4] = pw;
        }
        #pragma unroll
        for (int kk = 0; kk < 2; ++kk) {
            bf16x8 pf = *(const bf16x8*)&Pb[wave][l16 * 72 + kk * 32 + quad * 8];
            #pragma unroll
            for (int jj = 0; jj < 4; ++jj) {
                bf16x8 vfr = *(const bf16x8*)&Vtl[(jj * 16 + l16) * 64 +
                                                  (((kk * 4 + quad) ^ (l16 & 7)) * 8)];
                o[jj] = __builtin_amdgcn_mfma_f32_16x16x32_bf16(vfr, pf, o[jj], 0, 0, 0);
            }
        }
    }

    float inv = 1.f / l_i;
    #pragma unroll
    for (int jj = 0; jj < 4; ++jj) {
        uint2 ow;
        ow.x = pack2(o[jj][0] * inv, o[jj][1] * inv);
        ow.y = pack2(o[jj][2] * inv, o[jj][3] * inv);
        *(uint2*)&Pb[wave][l16 * 72 + jj * 16 + quad * 4] = ow;
    }
    int qq = lane >> 2;
    int dseg = (lane & 3) * 16;
    uint4 r0 = *(const uint4*)&Pb[wave][qq * 72 + dseg];
    uint4 r1 = *(const uint4*)&Pb[wave][qq * 72 + dseg + 8];
    u16* dst = ctx + ((size_t)(b * SS + q0 + wave * 16 + qq)) * DD + h * DKK + dseg;
    *(uint4*)dst = r0;
    *(uint4*)(dst + 8) = r1;
}

// ---------------------------------------------------------------------------
// LayerNorm epilogues.
// ---------------------------------------------------------------------------
__global__ __launch_bounds__(256)
void ln_res(const u16* __restrict__ po, const float* __restrict__ query,
            const float* __restrict__ g, const float* __restrict__ bb,
            float* __restrict__ out)
{
    int row = blockIdx.x;
    int tid = threadIdx.x;
    int lane = tid & 63, wave = tid >> 6;
    size_t base = (size_t)row * DD + tid * 4;
    __align__(8) u16 tp[4];
    *(uint2*)tp = *(const uint2*)(po + base);
    float4 q4 = *(const float4*)(query + base);
    float x[4];
    x[0] = bf2f(tp[0]) + q4.x; x[1] = bf2f(tp[1]) + q4.y;
    x[2] = bf2f(tp[2]) + q4.z; x[3] = bf2f(tp[3]) + q4.w;
    float s1 = 0.f, s2 = 0.f;
    #pragma unroll
    for (int i = 0; i < 4; ++i) { s1 += x[i]; s2 += x[i] * x[i]; }
    #pragma unroll
    for (int off = 1; off < 64; off <<= 1) {
        s1 += __shfl_xor(s1, off, 64);
        s2 += __shfl_xor(s2, off, 64);
    }
    __shared__ float red1[4], red2[4];
    if (lane == 0) { red1[wave] = s1; red2[wave] = s2; }
    __syncthreads();
    float t1 = red1[0] + red1[1] + red1[2] + red1[3];
    float t2 = red2[0] + red2[1] + red2[2] + red2[3];
    float mean = t1 * (1.f / 1024.f);
    float var  = fmaxf(t2 * (1.f / 1024.f) - mean * mean, 0.f);
    float rstd = rsqrtf(var + 1e-5f);
    float4 g4 = *(const float4*)(g + tid * 4);
    float4 b4 = *(const float4*)(bb + tid * 4);
    float4 ov;
    ov.x = (x[0] - mean) * rstd * g4.x + b4.x;
    ov.y = (x[1] - mean) * rstd * g4.y + b4.y;
    ov.z = (x[2] - mean) * rstd * g4.z + b4.z;
    ov.w = (x[3] - mean) * rstd * g4.w + b4.w;
    *(float4*)(out + base) = ov;
}

__global__ __launch_bounds__(256)
void ln_res2(const float* __restrict__ p0, const float* __restrict__ p1,
             const float* __restrict__ query, const float* __restrict__ g,
             const float* __restrict__ bb, float* __restrict__ out)
{
    int row = blockIdx.x;
    int tid = threadIdx.x;
    int lane = tid & 63, wave = tid >> 6;
    size_t base = (size_t)row * DD + tid * 4;
    float4 a4 = *(const float4*)(p0 + base);
    float4 c4 = *(const float4*)(p1 + base);
    float4 q4 = *(const float4*)(query + base);
    float x[4];
    x[0] = a4.x + c4.x + q4.x; x[1] = a4.y + c4.y + q4.y;
    x[2] = a4.z + c4.z + q4.z; x[3] = a4.w + c4.w + q4.w;
    float s1 = 0.f, s2 = 0.f;
    #pragma unroll
    for (int i = 0; i < 4; ++i) { s1 += x[i]; s2 += x[i] * x[i]; }
    #pragma unroll
    for (int off = 1; off < 64; off <<= 1) {
        s1 += __shfl_xor(s1, off, 64);
        s2 += __shfl_xor(s2, off, 64);
    }
    __shared__ float red1[4], red2[4];
    if (lane == 0) { red1[wave] = s1; red2[wave] = s2; }
    __syncthreads();
    float t1 = red1[0] + red1[1] + red1[2] + red1[3];
    float t2 = red2[0] + red2[1] + red2[2] + red2[3];
    float mean = t1 * (1.f / 1024.f);
    float var  = fmaxf(t2 * (1.f / 1024.f) - mean * mean, 0.f);
    float rstd = rsqrtf(var + 1e-5f);
    float4 g4 = *(const float4*)(g + tid * 4);
    float4 b4 = *(const float4*)(bb + tid * 4);
    float4 ov;
    ov.x = (x[0] - mean) * rstd * g4.x + b4.x;
    ov.y = (x[1] - mean) * rstd * g4.y + b4.y;
    ov.z = (x[2] - mean) * rstd * g4.z + b4.z;
    ov.w = (x[3] - mean) * rstd * g4.w + b4.w;
    *(float4*)(out + base) = ov;
}

extern "C" void kernel_launch(void* const* d_in, const int* in_sizes, int n_in,
                              void* d_out, int out_size, void* d_ws, size_t ws_size,
                              hipStream_t stream)
{
    const float* query = (const float*)d_in[0];
    const float* key   = (const float*)d_in[1];
    const float* value = (const float*)d_in[2];
    const float* comp  = (const float*)d_in[3];
    // d_in[4] = mask (causal tril) — computed analytically, ignored
    const float* wq = (const float*)d_in[5];
    const float* bq = (const float*)d_in[6];
    const float* wk = (const float*)d_in[7];
    const float* bk = (const float*)d_in[8];
    const float* wv = (const float*)d_in[9];
    const float* bv = (const float*)d_in[10];
    const float* wo = (const float*)d_in[11];
    const float* bo = (const float*)d_in[12];
    const float* lng = (const float*)d_in[13];
    const float* lnb = (const float*)d_in[14];
    const float* cpen = (const float*)d_in[15];
    float* outp = (float*)d_out;

    const size_t NE = (size_t)MROWS * DD;    // 4 Mi elements
    const size_t WE = (size_t)DD * DD;       // 1 Mi elements
    u16* wbf = (u16*)d_out;
    u16* cxr = wbf + 4 * WE;

    cvt_w<<<dim3(512, 4), 256, 0, stream>>>(wq, wk, wv, wo, wbf);

    if (ws_size >= (size_t)32 * 1024 * 1024) {
        u16* qh = (u16*)d_ws;
        u16* kh = qh + NE;
        u16* vt = kh + NE;
        float* P0 = (float*)d_ws;
        float* P1 = P0 + NE;

        qkv_gemm<<<dim3(256, 3), 256, 0, stream>>>(query, key, value, wbf,
                                                   bq, bk, bv, qh, kh, vt);
        attn6<<<1024, 256, 0, stream>>>(qh, kh, vt, comp, cpen, cxr);
        gemm_osk<<<dim3(256, 2), 256, 0, stream>>>(cxr, wbf + 3 * WE, bo, P0);
        ln_res2<<<MROWS, 256, 0, stream>>>(P0, P1, query, lng, lnb, outp);
    } else {
        u16* qh = (u16*)d_ws;
        u16* kh = qh + NE;
        u16* vt = kh + NE;
        u16* po = kh;

        cvt_x<<<2048, 256, 0, stream>>>(query, cxr);
        gemm_nt<0><<<256, 256, 0, stream>>>(cxr, wbf + 0 * WE, bq, qh);
        cvt_x<<<2048, 256, 0, stream>>>(key, cxr);
        gemm_nt<0><<<256, 256, 0, stream>>>(cxr, wbf + 1 * WE, bk, kh);
        cvt_x<<<2048, 256, 0, stream>>>(value, cxr);
        gemm_nt<2><<<256, 256, 0, stream>>>(cxr, wbf + 2 * WE, bv, vt);
        attn6<<<1024, 256, 0, stream>>>(qh, kh, vt, comp, cpen, cxr);
        gemm_nt<1><<<256, 256, 0, stream>>>(cxr, wbf + 3 * WE, bo, po);
        ln_res<<<MROWS, 256, 0, stream>>>(po, query, lng, lnb, outp);
    }
}

// Round 12
// 268.287 us; speedup vs baseline: 1.0290x; 1.0290x over previous
//
#include <hip/hip_runtime.h>

#define BB 2
#define SS 2048
#define DD 1024
#define HH 16
#define DKK 64
#define MROWS (BB*SS)
#define NEG_BIG (-30000.0f)

typedef unsigned short u16;
typedef unsigned int u32;
typedef __bf16 bf16x8 __attribute__((ext_vector_type(8)));
typedef float f32x4 __attribute__((ext_vector_type(4)));

__device__ __forceinline__ u16 f2bf(float f) {
    union { float f; u32 i; } w; w.f = f;
    u32 u = w.i;
    return (u16)((u + 0x7fffu + ((u >> 16) & 1u)) >> 16);
}
__device__ __forceinline__ float bf2f(u16 u) {
    union { u32 i; float f; } w; w.i = ((u32)u) << 16; return w.f;
}
__device__ __forceinline__ u32 pack2(float lo, float hi) {
    union { float f; u32 i; } a, b; a.f = lo; b.f = hi;
    return (a.i >> 16) | (b.i & 0xffff0000u);
}
__device__ __forceinline__ void gl2lds16(const u16* g, u16* l) {
    __builtin_amdgcn_global_load_lds(
        (const __attribute__((address_space(1))) void*)g,
        (__attribute__((address_space(3))) void*)l, 16, 0, 0);
}

// ---------------------------------------------------------------------------
// f32 -> bf16 converters.
// ---------------------------------------------------------------------------
__global__ __launch_bounds__(256)
void cvt_w(const float* __restrict__ w0, const float* __restrict__ w1,
           const float* __restrict__ w2, const float* __restrict__ w3,
           u16* __restrict__ dst)
{
    const float* srcs[4] = {w0, w1, w2, w3};
    const float* s = srcs[blockIdx.y];
    int i = (blockIdx.x * 256 + threadIdx.x) * 8;
    float4 a = *(const float4*)(s + i);
    float4 b = *(const float4*)(s + i + 4);
    uint4 o;
    o.x = pack2(a.x, a.y); o.y = pack2(a.z, a.w);
    o.z = pack2(b.x, b.y); o.w = pack2(b.z, b.w);
    *(uint4*)(dst + (size_t)blockIdx.y * DD * DD + i) = o;
}

__global__ __launch_bounds__(256)
void cvt_x(const float* __restrict__ s, u16* __restrict__ dst)
{
    int i = (blockIdx.x * 256 + threadIdx.x) * 8;
    float4 a = *(const float4*)(s + i);
    float4 b = *(const float4*)(s + i + 4);
    uint4 o;
    o.x = pack2(a.x, a.y); o.y = pack2(a.z, a.w);
    o.z = pack2(b.x, b.y); o.w = pack2(b.z, b.w);
    *(uint4*)(dst + i) = o;
}

// ---------------------------------------------------------------------------
// Fused QKV GEMM (round-10 proven config): grid (256, 3). y selects {Q,K,V}.
// A read as f32, packed to bf16 during staging. W via global_load_lds.
// XOR-swizzled LDS. bm=blk>>3, bn=blk&7 (plain mapping), (256,2).
// ---------------------------------------------------------------------------
__global__ __launch_bounds__(256, 2)
void qkv_gemm(const float* __restrict__ qf, const float* __restrict__ kf,
              const float* __restrict__ vf, const u16* __restrict__ wbf,
              const float* __restrict__ bq, const float* __restrict__ bk,
              const float* __restrict__ bv,
              u16* __restrict__ qh, u16* __restrict__ kh, u16* __restrict__ vt)
{
    __shared__ __align__(16) u16 smem[16384];
    u16* As = smem;
    u16* Bs = smem + 8192;
    const int K = 1024;
    int y = blockIdx.y;
    const float* A = (y == 0) ? qf : (y == 1) ? kf : vf;
    const u16* Wb = wbf + (size_t)y * DD * DD;
    const float* bias = (y == 0) ? bq : (y == 1) ? bk : bv;
    u16* out = (y == 0) ? qh : (y == 1) ? kh : vt;

    int tid  = threadIdx.x;
    int wave = tid >> 6, lane = tid & 63;
    int quad = lane >> 4, l16 = lane & 15;
    int bm = blockIdx.x >> 3;
    int bn = blockIdx.x & 7;
    int row0 = bm * 128, col0 = bn * 128;
    int wm = (wave >> 1) * 64, wn = (wave & 1) * 64;

    int srow = tid >> 3;
    int scol = (tid & 7) * 8;
    int swz  = ((tid & 7) ^ ((tid >> 3) & 7)) * 8;
    int bswz = ((lane & 7) ^ ((lane >> 3) & 7)) * 8;

    f32x4 acc[4][4] = {};

    for (int k0 = 0; k0 < K; k0 += 64) {
        uint4 av[4];
        #pragma unroll
        for (int c = 0; c < 4; ++c) {
            const float* ap = A + (size_t)(row0 + srow + c * 32) * K + k0 + scol;
            float4 lo = *(const float4*)ap;
            float4 hi = *(const float4*)(ap + 4);
            av[c].x = pack2(lo.x, lo.y); av[c].y = pack2(lo.z, lo.w);
            av[c].z = pack2(hi.x, hi.y); av[c].w = pack2(hi.z, hi.w);
        }
        __syncthreads();
        #pragma unroll
        for (int c = 0; c < 4; ++c)
            *(uint4*)&As[(srow + c * 32) * 64 + swz] = av[c];
        #pragma unroll
        for (int c = 0; c < 4; ++c) {
            int r0 = (c * 4 + wave) * 8;
            gl2lds16(Wb + (size_t)(col0 + r0 + (lane >> 3)) * K + k0 + bswz,
                     Bs + r0 * 64);
        }
        __syncthreads();
        #pragma unroll
        for (int kk = 0; kk < 2; ++kk) {
            bf16x8 af[4], bfv[4];
            #pragma unroll
            for (int i = 0; i < 4; ++i)
                af[i] = *(const bf16x8*)&As[(wm + i * 16 + l16) * 64 +
                                            (((kk * 4 + quad) ^ (l16 & 7)) * 8)];
            #pragma unroll
            for (int j = 0; j < 4; ++j)
                bfv[j] = *(const bf16x8*)&Bs[(wn + j * 16 + l16) * 64 +
                                             (((kk * 4 + quad) ^ (l16 & 7)) * 8)];
            #pragma unroll
            for (int i = 0; i < 4; ++i)
                #pragma unroll
                for (int j = 0; j < 4; ++j)
                    acc[i][j] = __builtin_amdgcn_mfma_f32_16x16x32_bf16(af[i], bfv[j], acc[i][j], 0, 0, 0);
        }
    }

    if (y == 2) {
        u16* Ct = smem;   // [dk 64][s 128] stride 136
        int b = row0 >> 11;
        int s0 = row0 & (SS - 1);
        #pragma unroll
        for (int p = 0; p < 2; ++p) {
            __syncthreads();
            if ((wave & 1) == p) {
                #pragma unroll
                for (int j = 0; j < 4; ++j) {
                    int dkl = j * 16 + l16;
                    float bvv = bias[col0 + p * 64 + dkl];
                    #pragma unroll
                    for (int i = 0; i < 4; ++i) {
                        uint2 pw;
                        pw.x = pack2(acc[i][j][0] + bvv, acc[i][j][1] + bvv);
                        pw.y = pack2(acc[i][j][2] + bvv, acc[i][j][3] + bvv);
                        *(uint2*)&Ct[dkl * 136 + wm + i * 16 + quad * 4] = pw;
                    }
                }
            }
            __syncthreads();
            int dkl = tid >> 2, seg = (tid & 3) * 32;
            int n = col0 + p * 64 + dkl;
            int h = n >> 6, dk = n & 63;
            u16* dst = out + (((size_t)(b * HH + h)) * DKK + dk) * SS + s0 + seg;
            #pragma unroll
            for (int u = 0; u < 4; ++u)
                *(uint4*)(dst + u * 8) = *(const uint4*)&Ct[dkl * 136 + seg + u * 8];
        }
        return;
    }

    #pragma unroll
    for (int j = 0; j < 4; ++j) {
        int n = col0 + wn + j * 16 + l16;
        float bvv = bias[n];
        #pragma unroll
        for (int i = 0; i < 4; ++i) {
            int rbase = row0 + wm + i * 16 + quad * 4;
            #pragma unroll
            for (int r = 0; r < 4; ++r) {
                int m = rbase + r;
                int b = m >> 11, s = m & (SS - 1);
                int h = n >> 6, dk = n & 63;
                out[(((size_t)(b * HH + h)) * SS + s) * DKK + dk] = f2bf(acc[i][j][r] + bvv);
            }
        }
    }
}

// ---------------------------------------------------------------------------
// Split-K O-proj (round-10 config): grid (256, 2); y = K-half. f32 partials.
// ---------------------------------------------------------------------------
__global__ __launch_bounds__(256, 2)
void gemm_osk(const u16* __restrict__ A, const u16* __restrict__ Wb,
              const float* __restrict__ bias, float* __restrict__ P)
{
    __shared__ __align__(16) u16 smem[16384];
    u16* As = smem;
    u16* Bs = smem + 8192;
    const int K = 1024;
    int khalf = blockIdx.y;
    int tid  = threadIdx.x;
    int wave = tid >> 6, lane = tid & 63;
    int quad = lane >> 4, l16 = lane & 15;
    int bm = blockIdx.x >> 3;
    int bn = blockIdx.x & 7;
    int row0 = bm * 128, col0 = bn * 128;
    int wm = (wave >> 1) * 64, wn = (wave & 1) * 64;
    int bswz = ((lane & 7) ^ ((lane >> 3) & 7)) * 8;

    f32x4 acc[4][4] = {};

    for (int k0 = khalf * 512; k0 < khalf * 512 + 512; k0 += 64) {
        __syncthreads();
        #pragma unroll
        for (int c = 0; c < 4; ++c) {
            int r0 = (c * 4 + wave) * 8;
            gl2lds16(A  + (size_t)(row0 + r0 + (lane >> 3)) * K + k0 + bswz,
                     As + r0 * 64);
            gl2lds16(Wb + (size_t)(col0 + r0 + (lane >> 3)) * K + k0 + bswz,
                     Bs + r0 * 64);
        }
        __syncthreads();
        #pragma unroll
        for (int kk = 0; kk < 2; ++kk) {
            bf16x8 af[4], bfv[4];
            #pragma unroll
            for (int i = 0; i < 4; ++i)
                af[i] = *(const bf16x8*)&As[(wm + i * 16 + l16) * 64 +
                                            (((kk * 4 + quad) ^ (l16 & 7)) * 8)];
            #pragma unroll
            for (int j = 0; j < 4; ++j)
                bfv[j] = *(const bf16x8*)&Bs[(wn + j * 16 + l16) * 64 +
                                             (((kk * 4 + quad) ^ (l16 & 7)) * 8)];
            #pragma unroll
            for (int i = 0; i < 4; ++i)
                #pragma unroll
                for (int j = 0; j < 4; ++j)
                    acc[i][j] = __builtin_amdgcn_mfma_f32_16x16x32_bf16(af[i], bfv[j], acc[i][j], 0, 0, 0);
        }
    }

    float* Pd = P + (size_t)khalf * MROWS * DD;
    #pragma unroll
    for (int j = 0; j < 4; ++j) {
        int n = col0 + wn + j * 16 + l16;
        float bvv = (khalf == 0) ? bias[n] : 0.f;
        #pragma unroll
        for (int i = 0; i < 4; ++i) {
            int rbase = row0 + wm + i * 16 + quad * 4;
            #pragma unroll
            for (int r = 0; r < 4; ++r)
                Pd[(size_t)(rbase + r) * DD + n] = acc[i][j][r] + bvv;
        }
    }
}

// ---------------------------------------------------------------------------
// Layout-B GEMM (sequential fallback path; unswizzled, proven).
// ---------------------------------------------------------------------------
template<int MODE>
__global__ __launch_bounds__(256, 2)
void gemm_nt(const u16* __restrict__ A, const u16* __restrict__ Wb,
             const float* __restrict__ bias, u16* __restrict__ out)
{
    __shared__ __align__(16) u16 smem[16384];
    u16* As = smem;
    u16* Bs = smem + 8192;
    const int K = 1024;
    int tid  = threadIdx.x;
    int wave = tid >> 6, lane = tid & 63;
    int quad = lane >> 4, l16 = lane & 15;
    int bm = blockIdx.x >> 3;
    int bn = blockIdx.x & 7;
    int row0 = bm * 128, col0 = bn * 128;
    int wm = (wave >> 1) * 64, wn = (wave & 1) * 64;

    f32x4 acc[4][4] = {};

    for (int k0 = 0; k0 < K; k0 += 64) {
        __syncthreads();
        #pragma unroll
        for (int c = 0; c < 4; ++c) {
            int r0 = (c * 4 + wave) * 8;
            gl2lds16(A  + (size_t)(row0 + r0 + (lane >> 3)) * K + k0 + (lane & 7) * 8,
                     As + r0 * 64);
            gl2lds16(Wb + (size_t)(col0 + r0 + (lane >> 3)) * K + k0 + (lane & 7) * 8,
                     Bs + r0 * 64);
        }
        __syncthreads();
        #pragma unroll
        for (int kk = 0; kk < 2; ++kk) {
            bf16x8 af[4], bfv[4];
            #pragma unroll
            for (int i = 0; i < 4; ++i)
                af[i] = *(const bf16x8*)&As[(wm + i * 16 + l16) * 64 + kk * 32 + quad * 8];
            #pragma unroll
            for (int j = 0; j < 4; ++j)
                bfv[j] = *(const bf16x8*)&Bs[(wn + j * 16 + l16) * 64 + kk * 32 + quad * 8];
            #pragma unroll
            for (int i = 0; i < 4; ++i)
                #pragma unroll
                for (int j = 0; j < 4; ++j)
                    acc[i][j] = __builtin_amdgcn_mfma_f32_16x16x32_bf16(af[i], bfv[j], acc[i][j], 0, 0, 0);
        }
    }

    if (MODE == 2) {
        u16* Ct = smem;
        int b = row0 >> 11;
        int s0 = row0 & (SS - 1);
        #pragma unroll
        for (int p = 0; p < 2; ++p) {
            __syncthreads();
            if ((wave & 1) == p) {
                #pragma unroll
                for (int j = 0; j < 4; ++j) {
                    int dkl = j * 16 + l16;
                    float bvv = bias[col0 + p * 64 + dkl];
                    #pragma unroll
                    for (int i = 0; i < 4; ++i) {
                        uint2 pw;
                        pw.x = pack2(acc[i][j][0] + bvv, acc[i][j][1] + bvv);
                        pw.y = pack2(acc[i][j][2] + bvv, acc[i][j][3] + bvv);
                        *(uint2*)&Ct[dkl * 136 + wm + i * 16 + quad * 4] = pw;
                    }
                }
            }
            __syncthreads();
            int dkl = tid >> 2, seg = (tid & 3) * 32;
            int n = col0 + p * 64 + dkl;
            int h = n >> 6, dk = n & 63;
            u16* dst = out + (((size_t)(b * HH + h)) * DKK + dk) * SS + s0 + seg;
            #pragma unroll
            for (int u = 0; u < 4; ++u)
                *(uint4*)(dst + u * 8) = *(const uint4*)&Ct[dkl * 136 + seg + u * 8];
        }
        return;
    }

    #pragma unroll
    for (int j = 0; j < 4; ++j) {
        int n = col0 + wn + j * 16 + l16;
        float bvv = bias[n];
        #pragma unroll
        for (int i = 0; i < 4; ++i) {
            int rbase = row0 + wm + i * 16 + quad * 4;
            #pragma unroll
            for (int r = 0; r < 4; ++r) {
                int m = rbase + r;
                float v = acc[i][j][r] + bvv;
                if (MODE == 0) {
                    int b = m >> 11, s = m & (SS - 1);
                    int h = n >> 6, dk = n & 63;
                    out[(((size_t)(b * HH + h)) * SS + s) * DKK + dk] = f2bf(v);
                } else {
                    out[(size_t)m * DD + n] = f2bf(v);
                }
            }
        }
    }
}

// ---------------------------------------------------------------------------
// Flash attention v7: 128-key tiles (barriers halved vs attn6). Block = 4
// waves = 64 q-rows; K-tile 16 KB + V^T-tile 16 KB staged per iteration via
// global_load_lds with XOR swizzle. Transposed scores; in-lane softmax;
// per-wave P LDS (stride 136). Grid 1024 heavy-first. LDS ~49 KB, 3 blk/CU.
// ---------------------------------------------------------------------------
__global__ __launch_bounds__(256, 3)
void attn7(const u16* __restrict__ Qh, const u16* __restrict__ Kh,
           const u16* __restrict__ Vt, const float* __restrict__ comp,
           const float* __restrict__ cpen_p, u16* __restrict__ ctx)
{
    __shared__ __align__(16) u16 Kl[128 * 64];      // [k_row][dk] swizzled
    __shared__ __align__(16) u16 Vtl[64 * 128];     // [dk][k_col] swizzled
    __shared__ __align__(16) u16 Pb[4][16 * 136];   // per-wave [q][k0..127]

    int tid  = threadIdx.x;
    int wave = tid >> 6, lane = tid & 63;
    int quad = lane >> 4, l16 = lane & 15;
    int blk = blockIdx.x;
    int bh  = blk & 31;
    int qt  = 31 - (blk >> 5);        // heavy q-tiles dispatched first
    int q0  = qt * 64;
    int b = bh >> 4, h = bh & 15;
    float cpen = cpen_p[0];
    int lswz = ((lane & 7) ^ ((lane >> 3) & 7)) * 8;

    const u16* Qb = Qh + (size_t)bh * SS * DKK;
    const u16* Kb = Kh + (size_t)bh * SS * DKK;
    const u16* Vb = Vt + (size_t)bh * DKK * SS;   // [dk][s]

    int myq = q0 + wave * 16 + l16;
    bf16x8 qf0 = *(const bf16x8*)&Qb[(size_t)myq * DKK + quad * 8];
    bf16x8 qf1 = *(const bf16x8*)&Qb[(size_t)myq * DKK + 32 + quad * 8];

    f32x4 o[4] = {};
    float m_i = NEG_BIG, l_i = 0.f;

    int ktmax = (q0 + 63) >> 7;

    for (int kt = 0; kt <= ktmax; ++kt) {
        __syncthreads();
        if (wave < 2) {
            // K: 128 rows x 64, contiguous 16 KB; unit = 8 rows (1 KB)
            #pragma unroll
            for (int c = 0; c < 8; ++c) {
                int u = wave * 8 + c;
                gl2lds16(Kb + (size_t)kt * 8192 + u * 512 + (lane >> 3) * 64 + lswz,
                         Kl + u * 512);
            }
        } else {
            // V^T: 64 dk-rows x 128 cols; unit = 4 rows (1 KB)
            #pragma unroll
            for (int c = 0; c < 8; ++c) {
                int u = (wave - 2) * 8 + c;
                int vr = u * 4 + (lane >> 4);
                int vswz = ((lane & 15) ^ (vr & 7)) * 8;
                gl2lds16(Vb + (size_t)vr * SS + kt * 128 + vswz,
                         Vtl + u * 512);
            }
        }
        __syncthreads();

        // S^T tile: 128 keys x 16 queries per wave
        f32x4 sc[8];
        #pragma unroll
        for (int jj = 0; jj < 8; ++jj) {
            bf16x8 kf0 = *(const bf16x8*)&Kl[(jj * 16 + l16) * 64 + ((quad ^ (l16 & 7)) * 8)];
            bf16x8 kf1 = *(const bf16x8*)&Kl[(jj * 16 + l16) * 64 + (((4 + quad) ^ (l16 & 7)) * 8)];
            f32x4 z = {};
            z = __builtin_amdgcn_mfma_f32_16x16x32_bf16(kf0, qf0, z, 0, 0, 0);
            sc[jj] = __builtin_amdgcn_mfma_f32_16x16x32_bf16(kf1, qf1, z, 0, 0, 0);
        }
        bool diag = (kt == ktmax);
        #pragma unroll
        for (int jj = 0; jj < 8; ++jj) {
            f32x4 c4 = *(const f32x4*)&comp[b * SS + kt * 128 + jj * 16 + quad * 4];
            int kb0 = kt * 128 + jj * 16 + quad * 4;
            #pragma unroll
            for (int r = 0; r < 4; ++r) {
                float sv = sc[jj][r] * 0.125f - cpen * c4[r];
                if (diag && (kb0 + r > myq)) sv = NEG_BIG;
                sc[jj][r] = sv;
            }
        }
        float mx = NEG_BIG;
        #pragma unroll
        for (int jj = 0; jj < 8; ++jj)
            #pragma unroll
            for (int r = 0; r < 4; ++r) mx = fmaxf(mx, sc[jj][r]);
        mx = fmaxf(mx, __shfl_xor(mx, 16, 64));
        mx = fmaxf(mx, __shfl_xor(mx, 32, 64));
        float mnew = fmaxf(m_i, mx);
        float alpha = __expf(m_i - mnew);
        m_i = mnew;
        float ls = 0.f;
        #pragma unroll
        for (int jj = 0; jj < 8; ++jj)
            #pragma unroll
            for (int r = 0; r < 4; ++r) {
                float p = __expf(sc[jj][r] - mnew);
                sc[jj][r] = p;
                ls += p;
            }
        ls += __shfl_xor(ls, 16, 64);
        ls += __shfl_xor(ls, 32, 64);
        l_i = l_i * alpha + ls;
        #pragma unroll
        for (int jj = 0; jj < 4; ++jj)
            #pragma unroll
            for (int r = 0; r < 4; ++r) o[jj][r] *= alpha;

        // P^T -> per-wave LDS [q=l16][k 0..127] (stride 136), b64 writes
        #pragma unroll
        for (int jj = 0; jj < 8; ++jj) {
            uint2 pw;
            pw.x = pack2(sc[jj][0], sc[jj][1]);
            pw.y = pack2(sc[jj][2], sc[jj][3]);
            *(uint2*)&Pb[wave][l16 * 136 + jj * 16 + quad * 4] = pw;
        }
        // O^T += V^T P over 4 k-chunks of 32
        #pragma unroll
        for (int kk = 0; kk < 4; ++kk) {
            bf16x8 pf = *(const bf16x8*)&Pb[wave][l16 * 136 + kk * 32 + quad * 8];
            #pragma unroll
            for (int jj = 0; jj < 4; ++jj) {
                bf16x8 vfr = *(const bf16x8*)&Vtl[(jj * 16 + l16) * 128 +
                                                  (((kk * 4 + quad) ^ (l16 & 7)) * 8)];
                o[jj] = __builtin_amdgcn_mfma_f32_16x16x32_bf16(vfr, pf, o[jj], 0, 0, 0);
            }
        }
    }

    // epilogue: O^T[d][q] -> per-wave LDS transpose -> coalesced ctx store
    float inv = 1.f / l_i;
    #pragma unroll
    for (int jj = 0; jj < 4; ++jj) {
        uint2 ow;
        ow.x = pack2(o[jj][0] * inv, o[jj][1] * inv);
        ow.y = pack2(o[jj][2] * inv, o[jj][3] * inv);
        *(uint2*)&Pb[wave][l16 * 136 + jj * 16 + quad * 4] = ow;
    }
    int qq = lane >> 2;
    int dseg = (lane & 3) * 16;
    uint4 r0 = *(const uint4*)&Pb[wave][qq * 136 + dseg];
    uint4 r1 = *(const uint4*)&Pb[wave][qq * 136 + dseg + 8];
    u16* dst = ctx + ((size_t)(b * SS + q0 + wave * 16 + qq)) * DD + h * DKK + dseg;
    *(uint4*)dst = r0;
    *(uint4*)(dst + 8) = r1;
}

// ---------------------------------------------------------------------------
// LayerNorm epilogues.
// ---------------------------------------------------------------------------
__global__ __launch_bounds__(256)
void ln_res(const u16* __restrict__ po, const float* __restrict__ query,
            const float* __restrict__ g, const float* __restrict__ bb,
            float* __restrict__ out)
{
    int row = blockIdx.x;
    int tid = threadIdx.x;
    int lane = tid & 63, wave = tid >> 6;
    size_t base = (size_t)row * DD + tid * 4;
    __align__(8) u16 tp[4];
    *(uint2*)tp = *(const uint2*)(po + base);
    float4 q4 = *(const float4*)(query + base);
    float x[4];
    x[0] = bf2f(tp[0]) + q4.x; x[1] = bf2f(tp[1]) + q4.y;
    x[2] = bf2f(tp[2]) + q4.z; x[3] = bf2f(tp[3]) + q4.w;
    float s1 = 0.f, s2 = 0.f;
    #pragma unroll
    for (int i = 0; i < 4; ++i) { s1 += x[i]; s2 += x[i] * x[i]; }
    #pragma unroll
    for (int off = 1; off < 64; off <<= 1) {
        s1 += __shfl_xor(s1, off, 64);
        s2 += __shfl_xor(s2, off, 64);
    }
    __shared__ float red1[4], red2[4];
    if (lane == 0) { red1[wave] = s1; red2[wave] = s2; }
    __syncthreads();
    float t1 = red1[0] + red1[1] + red1[2] + red1[3];
    float t2 = red2[0] + red2[1] + red2[2] + red2[3];
    float mean = t1 * (1.f / 1024.f);
    float var  = fmaxf(t2 * (1.f / 1024.f) - mean * mean, 0.f);
    float rstd = rsqrtf(var + 1e-5f);
    float4 g4 = *(const float4*)(g + tid * 4);
    float4 b4 = *(const float4*)(bb + tid * 4);
    float4 ov;
    ov.x = (x[0] - mean) * rstd * g4.x + b4.x;
    ov.y = (x[1] - mean) * rstd * g4.y + b4.y;
    ov.z = (x[2] - mean) * rstd * g4.z + b4.z;
    ov.w = (x[3] - mean) * rstd * g4.w + b4.w;
    *(float4*)(out + base) = ov;
}

__global__ __launch_bounds__(256)
void ln_res2(const float* __restrict__ p0, const float* __restrict__ p1,
             const float* __restrict__ query, const float* __restrict__ g,
             const float* __restrict__ bb, float* __restrict__ out)
{
    int row = blockIdx.x;
    int tid = threadIdx.x;
    int lane = tid & 63, wave = tid >> 6;
    size_t base = (size_t)row * DD + tid * 4;
    float4 a4 = *(const float4*)(p0 + base);
    float4 c4 = *(const float4*)(p1 + base);
    float4 q4 = *(const float4*)(query + base);
    float x[4];
    x[0] = a4.x + c4.x + q4.x; x[1] = a4.y + c4.y + q4.y;
    x[2] = a4.z + c4.z + q4.z; x[3] = a4.w + c4.w + q4.w;
    float s1 = 0.f, s2 = 0.f;
    #pragma unroll
    for (int i = 0; i < 4; ++i) { s1 += x[i]; s2 += x[i] * x[i]; }
    #pragma unroll
    for (int off = 1; off < 64; off <<= 1) {
        s1 += __shfl_xor(s1, off, 64);
        s2 += __shfl_xor(s2, off, 64);
    }
    __shared__ float red1[4], red2[4];
    if (lane == 0) { red1[wave] = s1; red2[wave] = s2; }
    __syncthreads();
    float t1 = red1[0] + red1[1] + red1[2] + red1[3];
    float t2 = red2[0] + red2[1] + red2[2] + red2[3];
    float mean = t1 * (1.f / 1024.f);
    float var  = fmaxf(t2 * (1.f / 1024.f) - mean * mean, 0.f);
    float rstd = rsqrtf(var + 1e-5f);
    float4 g4 = *(const float4*)(g + tid * 4);
    float4 b4 = *(const float4*)(bb + tid * 4);
    float4 ov;
    ov.x = (x[0] - mean) * rstd * g4.x + b4.x;
    ov.y = (x[1] - mean) * rstd * g4.y + b4.y;
    ov.z = (x[2] - mean) * rstd * g4.z + b4.z;
    ov.w = (x[3] - mean) * rstd * g4.w + b4.w;
    *(float4*)(out + base) = ov;
}

extern "C" void kernel_launch(void* const* d_in, const int* in_sizes, int n_in,
                              void* d_out, int out_size, void* d_ws, size_t ws_size,
                              hipStream_t stream)
{
    const float* query = (const float*)d_in[0];
    const float* key   = (const float*)d_in[1];
    const float* value = (const float*)d_in[2];
    const float* comp  = (const float*)d_in[3];
    // d_in[4] = mask (causal tril) — computed analytically, ignored
    const float* wq = (const float*)d_in[5];
    const float* bq = (const float*)d_in[6];
    const float* wk = (const float*)d_in[7];
    const float* bk = (const float*)d_in[8];
    const float* wv = (const float*)d_in[9];
    const float* bv = (const float*)d_in[10];
    const float* wo = (const float*)d_in[11];
    const float* bo = (const float*)d_in[12];
    const float* lng = (const float*)d_in[13];
    const float* lnb = (const float*)d_in[14];
    const float* cpen = (const float*)d_in[15];
    float* outp = (float*)d_out;

    const size_t NE = (size_t)MROWS * DD;    // 4 Mi elements
    const size_t WE = (size_t)DD * DD;       // 1 Mi elements
    u16* wbf = (u16*)d_out;
    u16* cxr = wbf + 4 * WE;

    cvt_w<<<dim3(512, 4), 256, 0, stream>>>(wq, wk, wv, wo, wbf);

    if (ws_size >= (size_t)32 * 1024 * 1024) {
        u16* qh = (u16*)d_ws;
        u16* kh = qh + NE;
        u16* vt = kh + NE;
        float* P0 = (float*)d_ws;
        float* P1 = P0 + NE;

        qkv_gemm<<<dim3(256, 3), 256, 0, stream>>>(query, key, value, wbf,
                                                   bq, bk, bv, qh, kh, vt);
        attn7<<<1024, 256, 0, stream>>>(qh, kh, vt, comp, cpen, cxr);
        gemm_osk<<<dim3(256, 2), 256, 0, stream>>>(cxr, wbf + 3 * WE, bo, P0);
        ln_res2<<<MROWS, 256, 0, stream>>>(P0, P1, query, lng, lnb, outp);
    } else {
        u16* qh = (u16*)d_ws;
        u16* kh = qh + NE;
        u16* vt = kh + NE;
        u16* po = kh;

        cvt_x<<<2048, 256, 0, stream>>>(query, cxr);
        gemm_nt<0><<<256, 256, 0, stream>>>(cxr, wbf + 0 * WE, bq, qh);
        cvt_x<<<2048, 256, 0, stream>>>(key, cxr);
        gemm_nt<0><<<256, 256, 0, stream>>>(cxr, wbf + 1 * WE, bk, kh);
        cvt_x<<<2048, 256, 0, stream>>>(value, cxr);
        gemm_nt<2><<<256, 256, 0, stream>>>(cxr, wbf + 2 * WE, bv, vt);
        attn7<<<1024, 256, 0, stream>>>(qh, kh, vt, comp, cpen, cxr);
        gemm_nt<1><<<256, 256, 0, stream>>>(cxr, wbf + 3 * WE, bo, po);
        ln_res<<<MROWS, 256, 0, stream>>>(po, query, lng, lnb, outp);
    }
}